// Round 20
// baseline (73.919 us; speedup 1.0000x reference)
//
#include <hip/hip_runtime.h>
#include <hip/hip_bf16.h>
#include <math.h>

typedef float  f32x4 __attribute__((ext_vector_type(4)));
typedef short  s16x8 __attribute__((ext_vector_type(8)));
typedef short  s16x4 __attribute__((ext_vector_type(4)));
typedef unsigned short u16x4 __attribute__((ext_vector_type(4)));

__device__ inline unsigned short bfc(float f){
  __hip_bfloat16 h = __float2bfloat16(f);
  unsigned short u; __builtin_memcpy(&u, &h, 2); return u;
}

__device__ inline f32x4 mfma16(s16x4 a, s16x4 b, f32x4 c){
#if __has_builtin(__builtin_amdgcn_mfma_f32_16x16x16_bf16)
  return __builtin_amdgcn_mfma_f32_16x16x16_bf16(a, b, c, 0, 0, 0);
#elif __has_builtin(__builtin_amdgcn_mfma_f32_16x16x16bf16_1k)
  return __builtin_amdgcn_mfma_f32_16x16x16bf16_1k(a, b, c, 0, 0, 0);
#else
  asm("v_mfma_f32_16x16x16_bf16 %0, %1, %2, %0" : "+v"(c) : "v"(a), "v"(b));
  return c;
#endif
}

__device__ inline void gl_lds16(const unsigned short* g, unsigned short* l){
  __builtin_amdgcn_global_load_lds(
      (const __attribute__((address_space(1))) unsigned int*)g,
      (__attribute__((address_space(3))) unsigned int*)l, 16, 0, 0);
}

// ---- prep: qkv -> packed A-frags (y<3); y==3: 4 weights (x<512) + mask (512<=x<528) ----
__global__ __launch_bounds__(256) void prep(const float* __restrict__ q, const float* __restrict__ k,
                                            const float* __restrict__ v,
                                            const float* __restrict__ w0, const float* __restrict__ w1,
                                            const float* __restrict__ w2, const float* __restrict__ w3,
                                            const unsigned char* __restrict__ mask,
                                            unsigned short* __restrict__ AP, unsigned short* __restrict__ WP,
                                            float* __restrict__ mf){
  int y = blockIdx.y;
  int x = blockIdx.x;
  if (y < 3){
    int t = x * 256 + threadIdx.x;
    const float* src = y==0 ? q : (y==1 ? k : v);
    unsigned short* d = AP + (size_t)y * 2097152;
    int r = t >> 6, g = t & 63;
    const float* sp = src + (size_t)r * 512 + g * 8;
    f32x4 a0 = *(const f32x4*)sp;
    f32x4 a1 = *(const f32x4*)(sp + 4);
    s16x8 o = { (short)bfc(a0.x),(short)bfc(a0.y),(short)bfc(a0.z),(short)bfc(a0.w),
                (short)bfc(a1.x),(short)bfc(a1.y),(short)bfc(a1.z),(short)bfc(a1.w) };
    size_t off = ((size_t)(((r>>4)*16 + (g>>2))*64 + (g&3)*16 + (r&15))) * 8;
    *(s16x8*)(d + off) = o;
  } else if (x < 512){
    int yy = x >> 7;
    int t = (x & 127) * 256 + threadIdx.x;   // 0..32767
    const float* src = yy==0 ? w0 : yy==1 ? w1 : yy==2 ? w2 : w3;
    int c = t >> 6, g = t & 63;
    const float* sp = src + (size_t)c * 512 + g * 8;
    f32x4 a0 = *(const f32x4*)sp;
    f32x4 a1 = *(const f32x4*)(sp + 4);
    s16x8 o = { (short)bfc(a0.x),(short)bfc(a0.y),(short)bfc(a0.z),(short)bfc(a0.w),
                (short)bfc(a1.x),(short)bfc(a1.y),(short)bfc(a1.z),(short)bfc(a1.w) };
    size_t off = ((size_t)(((c>>4)*16 + (g>>2))*64 + (g&3)*16 + (c&15))) * 8;
    *(s16x8*)(WP + yy*262144 + off) = o;
  } else if (x < 528){
    int t = (x - 512) * 256 + threadIdx.x;   // 0..4095
    int b = t >> 11, kp = t & 2047;
    int korig = (kp & 255) * 8 + (kp >> 8);
    mf[t] = mask[b*2048 + korig] ? -1.442695e9f : 0.0f;
  }
}

// ---- 3 projections; z=0 -> row-major Pq; z=1 -> Kperm[bh][kappa][64];
// z=2 -> Vtp[bh][cb=128][d=64][k16]. All epilogues coalesced. 8 waves/EU.
__global__ __launch_bounds__(256, 8) void proj_gemm(const unsigned short* __restrict__ Ap,
    const unsigned short* __restrict__ Wp,
    const float* __restrict__ bq, const float* __restrict__ bk, const float* __restrict__ bv,
    unsigned short* __restrict__ pout, unsigned short* __restrict__ Vtp){
  int z = blockIdx.z;
  const unsigned short* A = Ap + (size_t)z * 2097152;
  const unsigned short* W = Wp + (size_t)z * 262144;
  const float* bias = z==0 ? bq : (z==1 ? bk : bv);

  int w = threadIdx.x >> 6, lane = threadIdx.x & 63;
  int lr = lane & 15, lg = lane >> 4;
  int rt = blockIdx.x * 4 + w;
  int bn = blockIdx.y;

  f32x4 acc[4] = {};
  const unsigned short* Abase = A + ((size_t)rt*8192 + lane*8);
  const unsigned short* Wbase = W + ((size_t)bn*32768 + lane*8);
#pragma unroll 4
  for (int kc = 0; kc < 16; ++kc){
    s16x8 af = *(const s16x8*)(Abase + kc*512);
#pragma unroll
    for (int n = 0; n < 4; ++n){
      s16x8 bf = *(const s16x8*)(Wbase + ((size_t)n*16 + kc)*512);
      acc[n] = __builtin_amdgcn_mfma_f32_16x16x32_bf16(af, bf, acc[n], 0, 0, 0);
    }
  }
  if (z == 0){
    unsigned short* out = pout;
    int orow = rt*16 + lg*4;
#pragma unroll
    for (int n = 0; n < 4; ++n){
      int col = bn*64 + n*16 + lr;
      float bv_ = bias[col];
#pragma unroll
      for (int r = 0; r < 4; ++r)
        out[(size_t)(orow + r)*512 + col] = bfc(acc[n][r] + bv_);
    }
  } else if (z == 1){
    int bh = (rt >> 7) * 8 + ((rt >> 4) & 7);
    unsigned short* kp_ = pout + 2097152 + (size_t)bh*131072;
    int kbase = (rt & 15)*16 + 256*bn;
#pragma unroll
    for (int n = 0; n < 4; ++n){
      int col = bn*64 + n*16 + lr;
      float bv_ = bias[col];
#pragma unroll
      for (int r = 0; r < 4; ++r)
        kp_[(size_t)(kbase + lg*4 + r)*64 + n*16 + lr] = bfc(acc[n][r] + bv_);
    }
  } else {
    int bh = (rt >> 7) * 8 + ((rt >> 4) & 7);
    unsigned short* chunk = Vtp + (size_t)bh*131072 + ((size_t)((rt & 15) + 16*bn))*1024;
#pragma unroll
    for (int n = 0; n < 4; ++n){
      int col = bn*64 + n*16 + lr;
      float bv_ = bias[col];
      u16x4 ov = { bfc(acc[n][0] + bv_), bfc(acc[n][1] + bv_),
                   bfc(acc[n][2] + bv_), bfc(acc[n][3] + bv_) };
      *(u16x4*)(chunk + (n*16 + lr)*16 + lg*4) = ov;
    }
  }
}

// ---- flash: R19 structure, verified 72.0us (XCD swizzle, fixed-ref softmax) ----
__global__ __launch_bounds__(512, 4) void flash(const unsigned short* __restrict__ Pq,
                                             const unsigned short* __restrict__ Kp,
                                             const unsigned short* __restrict__ Vtp,
                                             const float* __restrict__ mf,
                                             unsigned short* __restrict__ aout){
  int flat = blockIdx.x;
  int bid = (flat & 7) * 64 + (flat >> 3);
  int bh = bid >> 5;            // 0..15
  int qt = bid & 31;            // 0..31
  int b = bh >> 3, h = bh & 7;
  int w = threadIdx.x >> 6;     // 0..7
  int wq = w & 1, wk = w >> 1;  // 2 q-groups x 4 KV quarters
  int lane = threadIdx.x & 63;
  int lr = lane & 15, lg = lane >> 4;

  const unsigned short* Qh = Pq + (size_t)(b*2048 + h*256)*512;
  const unsigned short* Kh = Kp + (size_t)bh*131072 + (size_t)wk*32768;
  const unsigned short* Vq = Vtp + (size_t)bh*131072 + (size_t)wk*32768;
  const float* mp = mf + b*2048 + wk*512 + lg*4;

  __shared__ char smem[65536];
  unsigned short* ktile = (unsigned short*)smem;            // [dbuf2][wk4][32 x 128B]
  unsigned short* vtile = (unsigned short*)(smem + 32768);  // [dbuf2][wk4][32 x 128B]
  float* obuf = (float*)smem;                               // 12 x [64][16] after loop
  float* lbuf = (float*)(smem + 49152);                     // l[192]

  int krow_l = lane >> 3;
  int cxor  = (lane & 7) ^ krow_l;
  int kcol_l = cxor * 8;

  int vhalf32 = (cxor >> 2) * 32;
  int vkc = (cxor & 3) * 8;
  const unsigned short* kg0 = Kh + (size_t)(8*(wq*2+0) + krow_l)*64 + kcol_l;
  const unsigned short* kg1 = Kh + (size_t)(8*(wq*2+1) + krow_l)*64 + kcol_l;
  int vd0 = wq*16 + krow_l + vhalf32;
  const unsigned short* vg0 = Vq + (vkc>>4)*1024 + vd0*16 + (vkc & 15);
  const unsigned short* vg1 = vg0 + 128;

  s16x8 qf[2][2];
#pragma unroll
  for (int qq = 0; qq < 2; ++qq){
    int qrow = qt*64 + wq*32 + qq*16 + lr;
    qf[qq][0] = *(const s16x8*)(Qh + (size_t)qrow*64 + lg*8);
    qf[qq][1] = *(const s16x8*)(Qh + (size_t)qrow*64 + 32 + lg*8);
  }

  float l[2] = {0.f, 0.f};
  f32x4 accT[2][4] = {};
  int kswz = (lr & 7) * 16;

#define STAGE(dbuf) { \
    unsigned short* kd = ktile + ((dbuf)*4 + wk)*2048; \
    unsigned short* vd = vtile + ((dbuf)*4 + wk)*2048; \
    gl_lds16(kg0, kd + (wq*2+0)*512); \
    gl_lds16(kg1, kd + (wq*2+1)*512); \
    gl_lds16(vg0, vd + (wq*2+0)*512); \
    gl_lds16(vg1, vd + (wq*2+1)*512); \
    kg0 += 2048; kg1 += 2048; vg0 += 2048; vg1 += 2048; }

  STAGE(0)
  f32x4 cmv0 = *(const f32x4*)(mp);
  f32x4 cmv1 = *(const f32x4*)(mp + 16);
  mp += 32;
  __syncthreads();
  int cur = 0;

  for (int t = 0; t < 16; ++t){
    if (t < 15) STAGE(cur ^ 1)
    f32x4 nmv0, nmv1;
    if (t < 15){
      nmv0 = *(const f32x4*)(mp);
      nmv1 = *(const f32x4*)(mp + 16);
      mp += 32;
    }

    const char* kb = (const char*)(ktile + (cur*4 + wk)*2048);
    const char* vb = (const char*)(vtile + (cur*4 + wk)*2048);

    float s2[2][2][4];
    __builtin_amdgcn_s_setprio(1);
#pragma unroll
    for (int n = 0; n < 2; ++n){
      int krow = n*16 + lr;
      s16x8 kf0 = *(const s16x8*)(kb + krow*128 + ((lg*16) ^ kswz));
      s16x8 kf1 = *(const s16x8*)(kb + krow*128 + ((64 + lg*16) ^ kswz));
      f32x4 mv = n ? cmv1 : cmv0;
#pragma unroll
      for (int qq = 0; qq < 2; ++qq){
        f32x4 a = {};
        a = __builtin_amdgcn_mfma_f32_16x16x32_bf16(kf0, qf[qq][0], a, 0, 0, 0);
        a = __builtin_amdgcn_mfma_f32_16x16x32_bf16(kf1, qf[qq][1], a, 0, 0, 0);
#pragma unroll
        for (int r = 0; r < 4; ++r)
          s2[qq][n][r] = __builtin_fmaf(a[r], 0.18033688f, mv[r]);
      }
    }
    __builtin_amdgcn_s_setprio(0);

    s16x4 pf[2][2];
#pragma unroll
    for (int qq = 0; qq < 2; ++qq){
#pragma unroll
      for (int n = 0; n < 2; ++n){
        float p0 = __builtin_amdgcn_exp2f(s2[qq][n][0]);
        float p1 = __builtin_amdgcn_exp2f(s2[qq][n][1]);
        float p2 = __builtin_amdgcn_exp2f(s2[qq][n][2]);
        float p3 = __builtin_amdgcn_exp2f(s2[qq][n][3]);
        l[qq] += (p0 + p1) + (p2 + p3);
        pf[qq][n] = (s16x4){ (short)bfc(p0), (short)bfc(p1), (short)bfc(p2), (short)bfc(p3) };
      }
    }

    __builtin_amdgcn_s_setprio(1);
#pragma unroll
    for (int n = 0; n < 2; ++n){
#pragma unroll
      for (int nd = 0; nd < 4; ++nd){
        int vrow = (nd & 1)*16 + lr;
        int vchunk = ((nd >> 1)*4 + n*2 + (lg >> 1)) ^ (vrow & 7);
        s16x4 vf = *(const s16x4*)(vb + vrow*128 + vchunk*16 + (lg & 1)*8);
        accT[0][nd] = mfma16(vf, pf[0][n], accT[0][nd]);
        accT[1][nd] = mfma16(vf, pf[1][n], accT[1][nd]);
      }
    }
    __builtin_amdgcn_s_setprio(0);

    cmv0 = nmv0; cmv1 = nmv1;
    __syncthreads();
    cur ^= 1;
  }
#undef STAGE

  float lt[2];
#pragma unroll
  for (int qq = 0; qq < 2; ++qq){
    float x = l[qq] + __shfl_xor(l[qq], 16);
    lt[qq] = x + __shfl_xor(x, 32);
  }

  if (wk != 0){
    int j = wk - 1;
#pragma unroll
    for (int qq = 0; qq < 2; ++qq){
      int reg = j*4 + wq*2 + qq;
      if (lg == 0) lbuf[reg*16 + lr] = lt[qq];
#pragma unroll
      for (int nd = 0; nd < 4; ++nd)
        *(f32x4*)&obuf[((size_t)reg*64 + lane)*16 + nd*4] = accT[qq][nd];
    }
  }
  __syncthreads();
  if (wk == 0){
#pragma unroll
    for (int qq = 0; qq < 2; ++qq){
      float ltot = lt[qq];
#pragma unroll
      for (int j = 0; j < 3; ++j)
        ltot += lbuf[(j*4 + wq*2 + qq)*16 + lr];
      float inv = (ltot > 0.f) ? 1.f / ltot : 0.f;
      int q = qt*64 + wq*32 + qq*16 + lr;
      int rt = (b*2048 + q) >> 4;
#pragma unroll
      for (int nd = 0; nd < 4; ++nd){
        f32x4 o = accT[qq][nd];
#pragma unroll
        for (int j = 0; j < 3; ++j){
          int reg = j*4 + wq*2 + qq;
          f32x4 oj = *(const f32x4*)&obuf[((size_t)reg*64 + lane)*16 + nd*4];
          o += oj;
        }
        int g = h*8 + nd*2 + (lg >> 1);
        u16x4 ov = { bfc(o[0]*inv), bfc(o[1]*inv), bfc(o[2]*inv), bfc(o[3]*inv) };
        unsigned short* dp = aout + ((size_t)((rt*16 + (g>>2))*64 + (g&3)*16 + lr))*8 + (lg&1)*4;
        *(u16x4*)dp = ov;
      }
    }
  }
}

// ---- output projection: packed A x packed Wm -> fp32 row-major. 8 waves/EU. ----
__global__ __launch_bounds__(256, 8) void gemm_out(const unsigned short* __restrict__ Ap,
                                                const unsigned short* __restrict__ Wp,
                                                const float* __restrict__ bias,
                                                float* __restrict__ out){
  int w = threadIdx.x >> 6, lane = threadIdx.x & 63;
  int lr = lane & 15, lg = lane >> 4;
  int rt = blockIdx.x * 4 + w;
  int bn = blockIdx.y;
  f32x4 acc[4] = {};
  const unsigned short* Abase = Ap + ((size_t)rt*8192 + lane*8);
  const unsigned short* Wbase = Wp + ((size_t)bn*32768 + lane*8);
#pragma unroll 4
  for (int kc = 0; kc < 16; ++kc){
    s16x8 af = *(const s16x8*)(Abase + kc*512);
#pragma unroll
    for (int n = 0; n < 4; ++n){
      s16x8 bf = *(const s16x8*)(Wbase + ((size_t)n*16 + kc)*512);
      acc[n] = __builtin_amdgcn_mfma_f32_16x16x32_bf16(af, bf, acc[n], 0, 0, 0);
    }
  }
  int orow = rt*16 + lg*4;
#pragma unroll
  for (int n = 0; n < 4; ++n){
    int col = bn*64 + n*16 + lr;
    float bv_ = bias[col];
#pragma unroll
    for (int r = 0; r < 4; ++r)
      out[(size_t)(orow + r)*512 + col] = acc[n][r] + bv_;
  }
}

extern "C" void kernel_launch(void* const* d_in, const int* in_sizes, int n_in,
                              void* d_out, int out_size, void* d_ws, size_t ws_size,
                              hipStream_t stream) {
  const float* q  = (const float*)d_in[0];
  const float* k  = (const float*)d_in[1];
  const float* v  = (const float*)d_in[2];
  const unsigned char* mask = (const unsigned char*)d_in[3];
  const float* Wq = (const float*)d_in[4];
  const float* Wk = (const float*)d_in[5];
  const float* Wv = (const float*)d_in[6];
  const float* Wm = (const float*)d_in[7];
  const float* bq = (const float*)d_in[8];
  const float* bk = (const float*)d_in[9];
  const float* bv = (const float*)d_in[10];
  const float* bm = (const float*)d_in[11];

  unsigned short* ws = (unsigned short*)d_ws;
  unsigned short* WP   = ws;                       // 4 x 262144 (packed weights)
  float*          MF   = (float*)(ws + 1048576);   // 4096 floats (permuted mask addend)
  unsigned short* AP   = ws + 1056768;             // 3 x 2097152 (packed bf16 qkv)
  unsigned short* PQ   = ws + 7348224;             // Pq row-major + Kperm[bh][kappa][64]
  unsigned short* VT   = ws + 13639680;            // 2097152 (Vtp, permuted-key chunks)
  unsigned short* AO   = ws + 15736832;            // 2097152 (packed attn out)

  prep<<<dim3(1024, 4), 256, 0, stream>>>(q, k, v, Wq, Wk, Wv, Wm, mask, AP, WP, MF);
  proj_gemm<<<dim3(64, 8, 3), 256, 0, stream>>>(AP, WP, bq, bk, bv, PQ, VT);
  flash<<<dim3(512), 512, 0, stream>>>(PQ, PQ + 2097152, VT, MF, AO);
  gemm_out<<<dim3(64, 8), 256, 0, stream>>>(AO, WP + 3*262144, bm, (float*)d_out);
}

// Round 21
// 71.774 us; speedup vs baseline: 1.0299x; 1.0299x over previous
//
#include <hip/hip_runtime.h>
#include <hip/hip_bf16.h>
#include <math.h>

typedef float  f32x4 __attribute__((ext_vector_type(4)));
typedef short  s16x8 __attribute__((ext_vector_type(8)));
typedef short  s16x4 __attribute__((ext_vector_type(4)));
typedef unsigned short u16x4 __attribute__((ext_vector_type(4)));

__device__ inline unsigned short bfc(float f){
  __hip_bfloat16 h = __float2bfloat16(f);
  unsigned short u; __builtin_memcpy(&u, &h, 2); return u;
}

__device__ inline f32x4 mfma16(s16x4 a, s16x4 b, f32x4 c){
#if __has_builtin(__builtin_amdgcn_mfma_f32_16x16x16_bf16)
  return __builtin_amdgcn_mfma_f32_16x16x16_bf16(a, b, c, 0, 0, 0);
#elif __has_builtin(__builtin_amdgcn_mfma_f32_16x16x16bf16_1k)
  return __builtin_amdgcn_mfma_f32_16x16x16bf16_1k(a, b, c, 0, 0, 0);
#else
  asm("v_mfma_f32_16x16x16_bf16 %0, %1, %2, %0" : "+v"(c) : "v"(a), "v"(b));
  return c;
#endif
}

__device__ inline void gl_lds16(const unsigned short* g, unsigned short* l){
  __builtin_amdgcn_global_load_lds(
      (const __attribute__((address_space(1))) unsigned int*)g,
      (__attribute__((address_space(3))) unsigned int*)l, 16, 0, 0);
}

// ---- prep: qkv -> packed A-frags, weights -> packed B-frags, PERMUTED mask addend ----
__global__ __launch_bounds__(256) void prep(const float* __restrict__ q, const float* __restrict__ k,
                                            const float* __restrict__ v,
                                            const float* __restrict__ w0, const float* __restrict__ w1,
                                            const float* __restrict__ w2, const float* __restrict__ w3,
                                            const unsigned char* __restrict__ mask,
                                            unsigned short* __restrict__ AP, unsigned short* __restrict__ WP,
                                            float* __restrict__ mf){
  int y = blockIdx.y;
  int t = blockIdx.x * 256 + threadIdx.x;
  if (y < 3){
    const float* src = y==0 ? q : (y==1 ? k : v);
    unsigned short* d = AP + (size_t)y * 2097152;
    int r = t >> 6, g = t & 63;
    const float* sp = src + (size_t)r * 512 + g * 8;
    f32x4 a0 = *(const f32x4*)sp;
    f32x4 a1 = *(const f32x4*)(sp + 4);
    s16x8 o = { (short)bfc(a0.x),(short)bfc(a0.y),(short)bfc(a0.z),(short)bfc(a0.w),
                (short)bfc(a1.x),(short)bfc(a1.y),(short)bfc(a1.z),(short)bfc(a1.w) };
    size_t off = ((size_t)(((r>>4)*16 + (g>>2))*64 + (g&3)*16 + (r&15))) * 8;
    *(s16x8*)(d + off) = o;
  } else if (y < 7){
    if (blockIdx.x < 128){
      int yy = y - 3;
      const float* src = yy==0 ? w0 : yy==1 ? w1 : yy==2 ? w2 : w3;
      int c = t >> 6, g = t & 63;
      const float* sp = src + (size_t)c * 512 + g * 8;
      f32x4 a0 = *(const f32x4*)sp;
      f32x4 a1 = *(const f32x4*)(sp + 4);
      s16x8 o = { (short)bfc(a0.x),(short)bfc(a0.y),(short)bfc(a0.z),(short)bfc(a0.w),
                  (short)bfc(a1.x),(short)bfc(a1.y),(short)bfc(a1.z),(short)bfc(a1.w) };
      size_t off = ((size_t)(((c>>4)*16 + (g>>2))*64 + (g&3)*16 + (c&15))) * 8;
      *(s16x8*)(WP + yy*262144 + off) = o;
    }
  } else if (t < 4096){
    int b = t >> 11, kp = t & 2047;
    int korig = (kp & 255) * 8 + (kp >> 8);
    mf[t] = mask[b*2048 + korig] ? -1.442695e9f : 0.0f;
  }
}

// ---- 3 projections; z=0 -> row-major Pq; z=1 -> Kperm[bh][kappa][64];
// z=2 -> Vtp[bh][cb=128][d=64][k16]. All epilogues coalesced.
__global__ __launch_bounds__(256) void proj_gemm(const unsigned short* __restrict__ Ap,
    const unsigned short* __restrict__ Wp,
    const float* __restrict__ bq, const float* __restrict__ bk, const float* __restrict__ bv,
    unsigned short* __restrict__ pout, unsigned short* __restrict__ Vtp){
  int z = blockIdx.z;
  const unsigned short* A = Ap + (size_t)z * 2097152;
  const unsigned short* W = Wp + (size_t)z * 262144;
  const float* bias = z==0 ? bq : (z==1 ? bk : bv);

  int w = threadIdx.x >> 6, lane = threadIdx.x & 63;
  int lr = lane & 15, lg = lane >> 4;
  int rt = blockIdx.x * 4 + w;
  int bn = blockIdx.y;

  f32x4 acc[4] = {};
  const unsigned short* Abase = A + ((size_t)rt*8192 + lane*8);
  const unsigned short* Wbase = W + ((size_t)bn*32768 + lane*8);
#pragma unroll 4
  for (int kc = 0; kc < 16; ++kc){
    s16x8 af = *(const s16x8*)(Abase + kc*512);
#pragma unroll
    for (int n = 0; n < 4; ++n){
      s16x8 bf = *(const s16x8*)(Wbase + ((size_t)n*16 + kc)*512);
      acc[n] = __builtin_amdgcn_mfma_f32_16x16x32_bf16(af, bf, acc[n], 0, 0, 0);
    }
  }
  if (z == 0){
    unsigned short* out = pout;
    int orow = rt*16 + lg*4;
#pragma unroll
    for (int n = 0; n < 4; ++n){
      int col = bn*64 + n*16 + lr;
      float bv_ = bias[col];
#pragma unroll
      for (int r = 0; r < 4; ++r)
        out[(size_t)(orow + r)*512 + col] = bfc(acc[n][r] + bv_);
    }
  } else if (z == 1){
    int bh = (rt >> 7) * 8 + ((rt >> 4) & 7);
    unsigned short* kp_ = pout + 2097152 + (size_t)bh*131072;
    int kbase = (rt & 15)*16 + 256*bn;
#pragma unroll
    for (int n = 0; n < 4; ++n){
      int col = bn*64 + n*16 + lr;
      float bv_ = bias[col];
#pragma unroll
      for (int r = 0; r < 4; ++r)
        kp_[(size_t)(kbase + lg*4 + r)*64 + n*16 + lr] = bfc(acc[n][r] + bv_);
    }
  } else {
    int bh = (rt >> 7) * 8 + ((rt >> 4) & 7);
    unsigned short* chunk = Vtp + (size_t)bh*131072 + ((size_t)((rt & 15) + 16*bn))*1024;
#pragma unroll
    for (int n = 0; n < 4; ++n){
      int col = bn*64 + n*16 + lr;
      float bv_ = bias[col];
      u16x4 ov = { bfc(acc[n][0] + bv_), bfc(acc[n][1] + bv_),
                   bfc(acc[n][2] + bv_), bfc(acc[n][3] + bv_) };
      *(u16x4*)(chunk + (n*16 + lr)*16 + lg*4) = ov;
    }
  }
}

// ---- flash: R16 structure + XCD-aware block swizzle (T1). Verified 72.0us. ----
__global__ __launch_bounds__(512, 4) void flash(const unsigned short* __restrict__ Pq,
                                             const unsigned short* __restrict__ Kp,
                                             const unsigned short* __restrict__ Vtp,
                                             const float* __restrict__ mf,
                                             unsigned short* __restrict__ aout){
  int flat = blockIdx.x;
  int bid = (flat & 7) * 64 + (flat >> 3);
  int bh = bid >> 5;            // 0..15
  int qt = bid & 31;            // 0..31
  int b = bh >> 3, h = bh & 7;
  int w = threadIdx.x >> 6;     // 0..7
  int wq = w & 1, wk = w >> 1;  // 2 q-groups x 4 KV quarters
  int lane = threadIdx.x & 63;
  int lr = lane & 15, lg = lane >> 4;

  const unsigned short* Qh = Pq + (size_t)(b*2048 + h*256)*512;
  const unsigned short* Kh = Kp + (size_t)bh*131072 + (size_t)wk*32768;
  const unsigned short* Vq = Vtp + (size_t)bh*131072 + (size_t)wk*32768;
  const float* mp = mf + b*2048 + wk*512 + lg*4;

  __shared__ char smem[65536];
  unsigned short* ktile = (unsigned short*)smem;            // [dbuf2][wk4][32 x 128B]
  unsigned short* vtile = (unsigned short*)(smem + 32768);  // [dbuf2][wk4][32 x 128B]
  float* obuf = (float*)smem;                               // 12 x [64][16] after loop
  float* lbuf = (float*)(smem + 49152);                     // l[192]

  int krow_l = lane >> 3;
  int cxor  = (lane & 7) ^ krow_l;
  int kcol_l = cxor * 8;

  int vhalf32 = (cxor >> 2) * 32;
  int vkc = (cxor & 3) * 8;
  const unsigned short* kg0 = Kh + (size_t)(8*(wq*2+0) + krow_l)*64 + kcol_l;
  const unsigned short* kg1 = Kh + (size_t)(8*(wq*2+1) + krow_l)*64 + kcol_l;
  int vd0 = wq*16 + krow_l + vhalf32;
  const unsigned short* vg0 = Vq + (vkc>>4)*1024 + vd0*16 + (vkc & 15);
  const unsigned short* vg1 = vg0 + 128;

  s16x8 qf[2][2];
#pragma unroll
  for (int qq = 0; qq < 2; ++qq){
    int qrow = qt*64 + wq*32 + qq*16 + lr;
    qf[qq][0] = *(const s16x8*)(Qh + (size_t)qrow*64 + lg*8);
    qf[qq][1] = *(const s16x8*)(Qh + (size_t)qrow*64 + 32 + lg*8);
  }

  float l[2] = {0.f, 0.f};
  f32x4 accT[2][4] = {};
  int kswz = (lr & 7) * 16;

#define STAGE(dbuf) { \
    unsigned short* kd = ktile + ((dbuf)*4 + wk)*2048; \
    unsigned short* vd = vtile + ((dbuf)*4 + wk)*2048; \
    gl_lds16(kg0, kd + (wq*2+0)*512); \
    gl_lds16(kg1, kd + (wq*2+1)*512); \
    gl_lds16(vg0, vd + (wq*2+0)*512); \
    gl_lds16(vg1, vd + (wq*2+1)*512); \
    kg0 += 2048; kg1 += 2048; vg0 += 2048; vg1 += 2048; }

  STAGE(0)
  f32x4 cmv0 = *(const f32x4*)(mp);
  f32x4 cmv1 = *(const f32x4*)(mp + 16);
  mp += 32;
  __syncthreads();
  int cur = 0;

  for (int t = 0; t < 16; ++t){
    if (t < 15) STAGE(cur ^ 1)
    f32x4 nmv0, nmv1;
    if (t < 15){
      nmv0 = *(const f32x4*)(mp);
      nmv1 = *(const f32x4*)(mp + 16);
      mp += 32;
    }

    const char* kb = (const char*)(ktile + (cur*4 + wk)*2048);
    const char* vb = (const char*)(vtile + (cur*4 + wk)*2048);

    float s2[2][2][4];
    __builtin_amdgcn_s_setprio(1);
#pragma unroll
    for (int n = 0; n < 2; ++n){
      int krow = n*16 + lr;
      s16x8 kf0 = *(const s16x8*)(kb + krow*128 + ((lg*16) ^ kswz));
      s16x8 kf1 = *(const s16x8*)(kb + krow*128 + ((64 + lg*16) ^ kswz));
      f32x4 mv = n ? cmv1 : cmv0;
#pragma unroll
      for (int qq = 0; qq < 2; ++qq){
        f32x4 a = {};
        a = __builtin_amdgcn_mfma_f32_16x16x32_bf16(kf0, qf[qq][0], a, 0, 0, 0);
        a = __builtin_amdgcn_mfma_f32_16x16x32_bf16(kf1, qf[qq][1], a, 0, 0, 0);
#pragma unroll
        for (int r = 0; r < 4; ++r)
          s2[qq][n][r] = __builtin_fmaf(a[r], 0.18033688f, mv[r]);
      }
    }
    __builtin_amdgcn_s_setprio(0);

    s16x4 pf[2][2];
#pragma unroll
    for (int qq = 0; qq < 2; ++qq){
#pragma unroll
      for (int n = 0; n < 2; ++n){
        float p0 = __builtin_amdgcn_exp2f(s2[qq][n][0]);
        float p1 = __builtin_amdgcn_exp2f(s2[qq][n][1]);
        float p2 = __builtin_amdgcn_exp2f(s2[qq][n][2]);
        float p3 = __builtin_amdgcn_exp2f(s2[qq][n][3]);
        l[qq] += (p0 + p1) + (p2 + p3);
        pf[qq][n] = (s16x4){ (short)bfc(p0), (short)bfc(p1), (short)bfc(p2), (short)bfc(p3) };
      }
    }

    __builtin_amdgcn_s_setprio(1);
#pragma unroll
    for (int n = 0; n < 2; ++n){
#pragma unroll
      for (int nd = 0; nd < 4; ++nd){
        int vrow = (nd & 1)*16 + lr;
        int vchunk = ((nd >> 1)*4 + n*2 + (lg >> 1)) ^ (vrow & 7);
        s16x4 vf = *(const s16x4*)(vb + vrow*128 + vchunk*16 + (lg & 1)*8);
        accT[0][nd] = mfma16(vf, pf[0][n], accT[0][nd]);
        accT[1][nd] = mfma16(vf, pf[1][n], accT[1][nd]);
      }
    }
    __builtin_amdgcn_s_setprio(0);

    cmv0 = nmv0; cmv1 = nmv1;
    __syncthreads();
    cur ^= 1;
  }
#undef STAGE

  float lt[2];
#pragma unroll
  for (int qq = 0; qq < 2; ++qq){
    float x = l[qq] + __shfl_xor(l[qq], 16);
    lt[qq] = x + __shfl_xor(x, 32);
  }

  if (wk != 0){
    int j = wk - 1;
#pragma unroll
    for (int qq = 0; qq < 2; ++qq){
      int reg = j*4 + wq*2 + qq;
      if (lg == 0) lbuf[reg*16 + lr] = lt[qq];
#pragma unroll
      for (int nd = 0; nd < 4; ++nd)
        *(f32x4*)&obuf[((size_t)reg*64 + lane)*16 + nd*4] = accT[qq][nd];
    }
  }
  __syncthreads();
  if (wk == 0){
#pragma unroll
    for (int qq = 0; qq < 2; ++qq){
      float ltot = lt[qq];
#pragma unroll
      for (int j = 0; j < 3; ++j)
        ltot += lbuf[(j*4 + wq*2 + qq)*16 + lr];
      float inv = (ltot > 0.f) ? 1.f / ltot : 0.f;
      int q = qt*64 + wq*32 + qq*16 + lr;
      int rt = (b*2048 + q) >> 4;
#pragma unroll
      for (int nd = 0; nd < 4; ++nd){
        f32x4 o = accT[qq][nd];
#pragma unroll
        for (int j = 0; j < 3; ++j){
          int reg = j*4 + wq*2 + qq;
          f32x4 oj = *(const f32x4*)&obuf[((size_t)reg*64 + lane)*16 + nd*4];
          o += oj;
        }
        int g = h*8 + nd*2 + (lg >> 1);
        u16x4 ov = { bfc(o[0]*inv), bfc(o[1]*inv), bfc(o[2]*inv), bfc(o[3]*inv) };
        unsigned short* dp = aout + ((size_t)((rt*16 + (g>>2))*64 + (g&3)*16 + lr))*8 + (lg&1)*4;
        *(u16x4*)dp = ov;
      }
    }
  }
}

// ---- output projection: packed A x packed Wm -> fp32 row-major ----
__global__ __launch_bounds__(256) void gemm_out(const unsigned short* __restrict__ Ap,
                                                const unsigned short* __restrict__ Wp,
                                                const float* __restrict__ bias,
                                                float* __restrict__ out){
  int w = threadIdx.x >> 6, lane = threadIdx.x & 63;
  int lr = lane & 15, lg = lane >> 4;
  int rt = blockIdx.x * 4 + w;
  int bn = blockIdx.y;
  f32x4 acc[4] = {};
  const unsigned short* Abase = Ap + ((size_t)rt*8192 + lane*8);
  const unsigned short* Wbase = Wp + ((size_t)bn*32768 + lane*8);
#pragma unroll 4
  for (int kc = 0; kc < 16; ++kc){
    s16x8 af = *(const s16x8*)(Abase + kc*512);
#pragma unroll
    for (int n = 0; n < 4; ++n){
      s16x8 bf = *(const s16x8*)(Wbase + ((size_t)n*16 + kc)*512);
      acc[n] = __builtin_amdgcn_mfma_f32_16x16x32_bf16(af, bf, acc[n], 0, 0, 0);
    }
  }
  int orow = rt*16 + lg*4;
#pragma unroll
  for (int n = 0; n < 4; ++n){
    int col = bn*64 + n*16 + lr;
    float bv_ = bias[col];
#pragma unroll
    for (int r = 0; r < 4; ++r)
      out[(size_t)(orow + r)*512 + col] = acc[n][r] + bv_;
  }
}

extern "C" void kernel_launch(void* const* d_in, const int* in_sizes, int n_in,
                              void* d_out, int out_size, void* d_ws, size_t ws_size,
                              hipStream_t stream) {
  const float* q  = (const float*)d_in[0];
  const float* k  = (const float*)d_in[1];
  const float* v  = (const float*)d_in[2];
  const unsigned char* mask = (const unsigned char*)d_in[3];
  const float* Wq = (const float*)d_in[4];
  const float* Wk = (const float*)d_in[5];
  const float* Wv = (const float*)d_in[6];
  const float* Wm = (const float*)d_in[7];
  const float* bq = (const float*)d_in[8];
  const float* bk = (const float*)d_in[9];
  const float* bv = (const float*)d_in[10];
  const float* bm = (const float*)d_in[11];

  unsigned short* ws = (unsigned short*)d_ws;
  unsigned short* WP   = ws;                       // 4 x 262144 (packed weights)
  float*          MF   = (float*)(ws + 1048576);   // 4096 floats (permuted mask addend)
  unsigned short* AP   = ws + 1056768;             // 3 x 2097152 (packed bf16 qkv)
  unsigned short* PQ   = ws + 7348224;             // Pq row-major + Kperm[bh][kappa][64]
  unsigned short* VT   = ws + 13639680;            // 2097152 (Vtp, permuted-key chunks)
  unsigned short* AO   = ws + 15736832;            // 2097152 (packed attn out)

  prep<<<dim3(1024, 8), 256, 0, stream>>>(q, k, v, Wq, Wk, Wv, Wm, mask, AP, WP, MF);
  proj_gemm<<<dim3(64, 8, 3), 256, 0, stream>>>(AP, WP, bq, bk, bv, PQ, VT);
  flash<<<dim3(512), 512, 0, stream>>>(PQ, PQ + 2097152, VT, MF, AO);
  gemm_out<<<dim3(64, 8), 256, 0, stream>>>(AO, WP + 3*262144, bm, (float*)d_out);
}